// Round 17
// baseline (138.270 us; speedup 1.0000x reference)
//
#include <hip/hip_runtime.h>
#include <math.h>

#define B_  1024
#define V_  3889
#define J_  33
#define NB_ 10
#define P_  288
#define N3  11667
#define NT_ 122            // 122 tiles of 96 cols (32 verts)
#define NPAD (NT_*96)      // 11712

typedef short bf16x8 __attribute__((ext_vector_type(8)));
typedef float f32x4  __attribute__((ext_vector_type(4)));

__device__ __forceinline__ unsigned short f2bf(float f) {
  union { float f; unsigned u; } v; v.f = f;
  unsigned r = v.u + 0x7FFFu + ((v.u >> 16) & 1u);
  return (unsigned short)(r >> 16);
}
__device__ __forceinline__ float bf2f(unsigned short h) {
  union { unsigned u; float f; } v; v.u = ((unsigned)h) << 16; return v.f;
}

// ---------------- kernel 1: fused prep (js | cvt | wbf roles by blockIdx)
// blocks [0,33): JS/bj   [33,399): pdT transpose   [399,463): wbf
#define PREP_JS   33
#define PREP_CVT  399
#define PREP_NB   463

__global__ __launch_bounds__(256) void k_prep(
    const float* __restrict__ Jreg, const float* __restrict__ vt,
    const float* __restrict__ sd, const float* __restrict__ pdirs,
    const float* __restrict__ lbsw,
    float* __restrict__ JS, float* __restrict__ bj,
    unsigned short* __restrict__ pdT, unsigned short* __restrict__ wbf)
{
  __shared__ __align__(16) unsigned char su[38016];   // union: cvt tile / js red
  const int bid = blockIdx.x;
  const int t = threadIdx.x;

  if (bid < PREP_JS) {
    float* red = (float*)su;                 // [33][128]
    const int j = bid;
    if (t < 128) {
      float acc[33];
      #pragma unroll
      for (int e = 0; e < 33; ++e) acc[e] = 0.f;
      for (int v = t; v < V_; v += 128) {
        float r = Jreg[j*V_ + v];
        #pragma unroll
        for (int c = 0; c < 3; ++c) {
          acc[c*11 + 10] += r * vt[v*3 + c];
          #pragma unroll
          for (int l = 0; l < NB_; ++l)
            acc[c*11 + l] += r * sd[v*30 + c*10 + l];
        }
      }
      #pragma unroll
      for (int e = 0; e < 33; ++e) red[e*128 + t] = acc[e];
    }
    __syncthreads();
    if (t < 33) {
      float s = 0.f;
      for (int i = 0; i < 128; ++i) s += red[t*128 + i];
      int c = t / 11, l = t % 11;
      if (l == 10) bj[j*3 + c] = s;
      else         JS[(j*3 + c)*NB_ + l] = s;
    }
  } else if (bid < PREP_CVT) {
    float* tile = (float*)su;                // [288][33]
    const int bb = bid - PREP_JS;
    const int nt = bb / 3;
    const int c0 = (bb % 3) * 32;
    for (int i = t; i < P_*32; i += 256) {
      int k = i >> 5, c = i & 31;
      int gc = nt*96 + c0 + c;
      tile[k*33 + c] = (gc < N3) ? pdirs[(size_t)k*N3 + gc] : 0.f;
    }
    __syncthreads();
    for (int o = t; o < 32*P_; o += 256) {
      int c = o / P_, k = o % P_;
      pdT[((size_t)(nt*96 + c0 + c))*P_ + k] = f2bf(tile[k*33 + c]);
    }
  } else {
    const int bb = bid - PREP_CVT;
    const int total = 4096*96;
    for (int i = bb*256 + t; i < total; i += 64*256) {
      int v = i / 96, k = i - 96*v;
      float val = 0.f;
      if (v < V_) {
        if (k < 33) val = lbsw[(size_t)v*33 + k];
        else if (k < 66) {
          float w = lbsw[(size_t)v*33 + (k-33)];
          val = w - bf2f(f2bf(w));
        }
      }
      wbf[i] = f2bf(val);
    }
  }
}

// ---------------- kernel 2: joints, Rodrigues, FK, pose_feat (bf16) + Abf direct
__global__ __launch_bounds__(64) void k_pose(
    const float* __restrict__ betas, const float* __restrict__ go,
    const float* __restrict__ bp, const float* __restrict__ JS,
    const float* __restrict__ bj,
    unsigned short* __restrict__ pfb,   // [B][288] bf16
    unsigned short* __restrict__ Abf)   // [B][16][96] bf16 (hi/lo split)
{
  const int b = blockIdx.x;
  const int t = threadIdx.x;
  __shared__ float rot[J_][9];
  __shared__ float jnt[J_][3];
  __shared__ float Ash[J_][12];
  __shared__ float bsh[NB_];
  if (t < NB_) bsh[t] = betas[b*NB_ + t];
  __syncthreads();
  if (t < J_) {
    #pragma unroll
    for (int c = 0; c < 3; ++c) {
      float s = bj[t*3 + c];
      #pragma unroll
      for (int l = 0; l < NB_; ++l) s += bsh[l] * JS[(t*3 + c)*NB_ + l];
      jnt[t][c] = s;
    }
    float px, py, pz;
    if (t == 0) { px = go[b*3+0]; py = go[b*3+1]; pz = go[b*3+2]; }
    else {
      const float* p = bp + (size_t)b*((J_-1)*3) + (t-1)*3;
      px = p[0]; py = p[1]; pz = p[2];
    }
    float ax = px + 1e-8f, ay = py + 1e-8f, az = pz + 1e-8f;
    float ang = sqrtf(ax*ax + ay*ay + az*az);
    float inv = 1.0f / ang;
    float ux = px*inv, uy = py*inv, uz = pz*inv;
    float sn = sinf(ang), cs = cosf(ang);
    float K[9] = {0.f,-uz,uy,  uz,0.f,-ux,  -uy,ux,0.f};
    float R[9];
    #pragma unroll
    for (int r = 0; r < 3; ++r)
      #pragma unroll
      for (int c = 0; c < 3; ++c) {
        float k2 = K[r*3+0]*K[0*3+c] + K[r*3+1]*K[1*3+c] + K[r*3+2]*K[2*3+c];
        float id = (r == c) ? 1.f : 0.f;
        R[r*3+c] = id + sn*K[r*3+c] + (1.f - cs)*k2;
      }
    #pragma unroll
    for (int e = 0; e < 9; ++e) rot[t][e] = R[e];
    if (t >= 1) {
      #pragma unroll
      for (int e = 0; e < 9; ++e)
        pfb[(size_t)b*P_ + (t-1)*9 + e] = f2bf(R[e] - ((e==0||e==4||e==8) ? 1.f : 0.f));
    }
  }
  __syncthreads();
  if (t == 0) {
    float G[12];
    #pragma unroll
    for (int r = 0; r < 3; ++r) {
      G[r*4+0] = rot[0][r*3+0]; G[r*4+1] = rot[0][r*3+1];
      G[r*4+2] = rot[0][r*3+2]; G[r*4+3] = jnt[0][r];
    }
    for (int j = 0; j < J_; ++j) {
      if (j > 0) {
        float rel0 = jnt[j][0] - jnt[j-1][0];
        float rel1 = jnt[j][1] - jnt[j-1][1];
        float rel2 = jnt[j][2] - jnt[j-1][2];
        float N[12];
        #pragma unroll
        for (int r = 0; r < 3; ++r) {
          #pragma unroll
          for (int c = 0; c < 3; ++c)
            N[r*4+c] = G[r*4+0]*rot[j][0*3+c] + G[r*4+1]*rot[j][1*3+c] + G[r*4+2]*rot[j][2*3+c];
          N[r*4+3] = G[r*4+0]*rel0 + G[r*4+1]*rel1 + G[r*4+2]*rel2 + G[r*4+3];
        }
        #pragma unroll
        for (int e = 0; e < 12; ++e) G[e] = N[e];
      }
      #pragma unroll
      for (int r = 0; r < 3; ++r) {
        Ash[j][r*4+0] = G[r*4+0];
        Ash[j][r*4+1] = G[r*4+1];
        Ash[j][r*4+2] = G[r*4+2];
        Ash[j][r*4+3] = G[r*4+3] - (G[r*4+0]*jnt[j][0] + G[r*4+1]*jnt[j][1] + G[r*4+2]*jnt[j][2]);
      }
    }
  }
  __syncthreads();
  const float* Af = &Ash[0][0];
  for (int i = t; i < 1536; i += 64) {
    int n = i / 96, k = i - 96*n;
    int j = (k < 33) ? k : ((k < 66) ? (k - 33) : -1);
    float val = 0.f;
    if (j >= 0) {
      if (n < 12) val = Af[j*12 + n];
      else if (n < 15) {
        float tr = Af[j*12 + (n-12)*4 + 3];
        val = tr - bf2f(f2bf(tr));
      }
    }
    Abf[(size_t)b*1536 + i] = f2bf(val);
  }
}

// ---------------- FUSED kernel: MFMA GEMM (v_posed) + MFMA skinning, pipelined, 4 blocks/CU
#define TS 17    // T row stride (floats): gcd(17,32)=1 -> conflict-free scalar reads

__global__ __launch_bounds__(256, 4) void k_gs(
    const float* __restrict__ betas,
    const float* __restrict__ vt, const float* __restrict__ sd,
    const unsigned short* __restrict__ pdT,
    const unsigned short* __restrict__ pfb_g,
    const float* __restrict__ transl,
    const unsigned short* __restrict__ wbf,   // [4096][96]
    const unsigned short* __restrict__ Abf,   // [B][16][96]
    float* __restrict__ out)
{
  __shared__ float s_beta[640];
  __shared__ float s_tr[192];           // transl for this block's 64 batches
  __shared__ float s_vp[64*100];        // v_posed tile [64 b][96 gc], stride 100
  __shared__ float s_T[4][32*TS];       // per-wave T tile (1 batch x 32 v), reused per h

  const int tid = threadIdx.x;
  const int nt = blockIdx.x, bt = blockIdx.y;
  const int b0 = bt*64;
  const int lane = tid & 63, wid = tid >> 6;
  const int wm = wid >> 1, wn = wid & 1;
  const int l15 = lane & 15, lg = lane >> 4;

  for (int i = tid; i < 64*NB_; i += 256) s_beta[i] = betas[(size_t)b0*NB_ + i];
  for (int i = tid; i < 192; i += 256) s_tr[i] = transl[(size_t)b0*3 + i];

  // hoisted skin a-frags (independent of GEMM; latency hides under phase 1)
  bf16x8 afr[2][3];
  #pragma unroll
  for (int mt = 0; mt < 2; ++mt) {
    const int vrow = nt*32 + mt*16 + l15;   // <= 3903 < 4096 (wbf zero-padded)
    #pragma unroll
    for (int ks = 0; ks < 3; ++ks)
      afr[mt][ks] = *(const bf16x8*)&wbf[(size_t)vrow*96 + ks*32 + lg*8];
  }
  __syncthreads();

  // ---- phase 1: GEMM (identical math to round-16) ----
  f32x4 acc[2][3];
  #pragma unroll
  for (int f = 0; f < 3; ++f) {
    int colL = wn*48 + f*16 + l15;
    int gc = nt*96 + colL;
    if (gc < N3) {
      int v = gc/3, c = gc - 3*v;
      float base = vt[gc];
      float sval[2][4];
      #pragma unroll
      for (int mi = 0; mi < 2; ++mi)
        #pragma unroll
        for (int reg = 0; reg < 4; ++reg) sval[mi][reg] = base;
      #pragma unroll
      for (int l = 0; l < NB_; ++l) {
        float sdv = sd[(size_t)v*30 + c*10 + l];
        #pragma unroll
        for (int mi = 0; mi < 2; ++mi) {
          int row_b = mi*32 + wm*16 + lg*4;
          #pragma unroll
          for (int reg = 0; reg < 4; ++reg)
            sval[mi][reg] += s_beta[(row_b+reg)*NB_ + l] * sdv;
        }
      }
      #pragma unroll
      for (int mi = 0; mi < 2; ++mi) {
        acc[mi][f][0]=sval[mi][0]; acc[mi][f][1]=sval[mi][1];
        acc[mi][f][2]=sval[mi][2]; acc[mi][f][3]=sval[mi][3];
      }
    } else {
      #pragma unroll
      for (int mi = 0; mi < 2; ++mi)
        acc[mi][f] = (f32x4){0.f,0.f,0.f,0.f};
    }
  }

  const unsigned short* __restrict__ pfrow0 =
      pfb_g + (size_t)(b0 + wm*16 + l15)*P_ + lg*8;
  const unsigned short* __restrict__ pfrow1 =
      pfb_g + (size_t)(b0 + 32 + wm*16 + l15)*P_ + lg*8;
  const unsigned short* __restrict__ pdrow =
      pdT + (size_t)(nt*96 + wn*48 + l15)*P_ + lg*8;
  #pragma unroll
  for (int ks = 0; ks < 9; ++ks) {
    bf16x8 a0 = *(const bf16x8*)(pfrow0 + ks*32);
    bf16x8 a1 = *(const bf16x8*)(pfrow1 + ks*32);
    #pragma unroll
    for (int f = 0; f < 3; ++f) {
      bf16x8 b = *(const bf16x8*)(pdrow + (size_t)f*16*P_ + ks*32);
      acc[0][f] = __builtin_amdgcn_mfma_f32_16x16x32_bf16(a0, b, acc[0][f], 0, 0, 0);
      acc[1][f] = __builtin_amdgcn_mfma_f32_16x16x32_bf16(a1, b, acc[1][f], 0, 0, 0);
    }
  }

  // prefetch g=0 skin b-frags (hides under phase-2 LDS writes + barrier)
  bf16x8 bcur[2][3];
  #pragma unroll
  for (int h = 0; h < 2; ++h) {
    const unsigned short* Ab = Abf + (size_t)(b0 + wid*16 + h)*1536;
    #pragma unroll
    for (int ks = 0; ks < 3; ++ks)
      bcur[h][ks] = *(const bf16x8*)&Ab[l15*96 + ks*32 + lg*8];
  }

  // ---- phase 2: v_posed -> LDS ----
  #pragma unroll
  for (int f = 0; f < 3; ++f) {
    int colL = wn*48 + f*16 + l15;
    #pragma unroll
    for (int mi = 0; mi < 2; ++mi) {
      int row_b = mi*32 + wm*16 + lg*4;
      #pragma unroll
      for (int reg = 0; reg < 4; ++reg)
        s_vp[(row_b+reg)*100 + colL] = acc[mi][f][reg];
    }
  }
  __syncthreads();

  // ---- phase 3: pipelined MFMA skinning (shared T tile, sequential h) ----
  float* Tw = &s_T[wid][0];
  const int vl = lane & 31;
  const int v = nt*32 + vl;

  float pxc[2], pyc[2], pzc[2];
  #pragma unroll
  for (int h = 0; h < 2; ++h) {
    int bl = wid*16 + h;
    pxc[h] = s_vp[bl*100 + vl*3 + 0];
    pyc[h] = s_vp[bl*100 + vl*3 + 1];
    pzc[h] = s_vp[bl*100 + vl*3 + 2];
  }

  #pragma unroll 2
  for (int g = 0; g < 8; ++g) {
    bf16x8 bnxt[2][3];
    float pxn[2] = {0.f,0.f}, pyn[2] = {0.f,0.f}, pzn[2] = {0.f,0.f};
    if (g < 7) {
      #pragma unroll
      for (int h = 0; h < 2; ++h) {
        const unsigned short* Ab = Abf + (size_t)(b0 + wid*16 + (g+1)*2 + h)*1536;
        #pragma unroll
        for (int ks = 0; ks < 3; ++ks)
          bnxt[h][ks] = *(const bf16x8*)&Ab[l15*96 + ks*32 + lg*8];
        int bln = wid*16 + (g+1)*2 + h;
        pxn[h] = s_vp[bln*100 + vl*3 + 0];
        pyn[h] = s_vp[bln*100 + vl*3 + 1];
        pzn[h] = s_vp[bln*100 + vl*3 + 2];
      }
    }

    #pragma unroll
    for (int h = 0; h < 2; ++h) {
      f32x4 t0 = {0.f,0.f,0.f,0.f}, t1 = t0;
      #pragma unroll
      for (int ks = 0; ks < 3; ++ks) {
        t0 = __builtin_amdgcn_mfma_f32_16x16x32_bf16(afr[0][ks], bcur[h][ks], t0, 0, 0, 0);
        t1 = __builtin_amdgcn_mfma_f32_16x16x32_bf16(afr[1][ks], bcur[h][ks], t1, 0, 0, 0);
      }
      // C layout: col=lane&15 (n), row=(lane>>4)*4+reg (vertex-local)
      #pragma unroll
      for (int reg = 0; reg < 4; ++reg) {
        Tw[(lg*4+reg)*TS + l15]    = t0[reg];
        Tw[(16+lg*4+reg)*TS + l15] = t1[reg];
      }
      // consume batch g*2+h (in-wave DS ordering: writes above retire first)
      {
        const int bl2 = wid*16 + g*2 + h;
        const int b2  = b0 + bl2;
        const float* Tr = Tw + vl*TS;
        float o0 = Tr[0]*pxc[h] + Tr[1]*pyc[h] + Tr[2]*pzc[h]  + Tr[3]  + Tr[12] + s_tr[bl2*3+0];
        float o1 = Tr[4]*pxc[h] + Tr[5]*pyc[h] + Tr[6]*pzc[h]  + Tr[7]  + Tr[13] + s_tr[bl2*3+1];
        float o2 = Tr[8]*pxc[h] + Tr[9]*pyc[h] + Tr[10]*pzc[h] + Tr[11] + Tr[14] + s_tr[bl2*3+2];
        if (lane < 32 && v < V_) {
          size_t po = (size_t)b2*N3 + (size_t)v*3;
          out[po+0] = o0; out[po+1] = o1; out[po+2] = o2;
        }
      }
    }

    if (g < 7) {
      #pragma unroll
      for (int h = 0; h < 2; ++h) {
        #pragma unroll
        for (int ks = 0; ks < 3; ++ks)
          bcur[h][ks] = bnxt[h][ks];
        pxc[h] = pxn[h]; pyc[h] = pyn[h]; pzc[h] = pzn[h];
      }
    }
  }
}

extern "C" void kernel_launch(void* const* d_in, const int* in_sizes, int n_in,
                              void* d_out, int out_size, void* d_ws, size_t ws_size,
                              hipStream_t stream) {
  const float* betas  = (const float*)d_in[0];
  const float* go     = (const float*)d_in[1];
  const float* bp     = (const float*)d_in[2];
  const float* transl = (const float*)d_in[3];
  const float* vt     = (const float*)d_in[4];
  const float* sd     = (const float*)d_in[5];
  const float* pdirs  = (const float*)d_in[6];
  const float* Jreg   = (const float*)d_in[7];
  const float* lbsw   = (const float*)d_in[8];
  float* out = (float*)d_out;
  char* wb = (char*)d_ws;

  // round-14/15-proven fused workspace layout (ws_size >= 12,899,328 verified).
  float* JS            = (float*)(wb + 0);
  float* bj            = (float*)(wb + 4096);
  unsigned short* pfb  = (unsigned short*)(wb + 1630720);   // 589,824
  unsigned short* Abf  = (unsigned short*)(wb + 2221056);   // 3,145,728
  unsigned short* pdT  = (unsigned short*)(wb + 5366784);   // 6,746,112
  unsigned short* wbf  = (unsigned short*)(wb + 12112896);  // 786,432 -> ends 12,899,328

  hipLaunchKernelGGL(k_prep, dim3(PREP_NB), dim3(256), 0, stream,
                     Jreg, vt, sd, pdirs, lbsw, JS, bj, pdT, wbf);
  hipLaunchKernelGGL(k_pose, dim3(B_), dim3(64), 0, stream,
                     betas, go, bp, JS, bj, pfb, Abf);
  hipLaunchKernelGGL(k_gs,   dim3(NT_, B_/64), dim3(256), 0, stream,
                     betas, vt, sd, pdT, pfb, transl, wbf, Abf, out);
}

// Round 18
// 107.373 us; speedup vs baseline: 1.2878x; 1.2878x over previous
//
#include <hip/hip_runtime.h>
#include <math.h>

#define B_  1024
#define V_  3889
#define J_  33
#define NB_ 10
#define P_  288
#define N3  11667
#define NT_ 122            // 122 tiles of 96 cols (32 verts)
#define NPAD (NT_*96)      // 11712

typedef short bf16x8 __attribute__((ext_vector_type(8)));
typedef float f32x4  __attribute__((ext_vector_type(4)));

__device__ __forceinline__ unsigned short f2bf(float f) {
  union { float f; unsigned u; } v; v.f = f;
  unsigned r = v.u + 0x7FFFu + ((v.u >> 16) & 1u);
  return (unsigned short)(r >> 16);
}
__device__ __forceinline__ float bf2f(unsigned short h) {
  union { unsigned u; float f; } v; v.u = ((unsigned)h) << 16; return v.f;
}

// ---------------- kernel 1: fused prep (js | cvt | wbf roles by blockIdx)
// blocks [0,33): JS/bj   [33,399): pdT transpose   [399,463): wbf
#define PREP_JS   33
#define PREP_CVT  399
#define PREP_NB   463

__global__ __launch_bounds__(256) void k_prep(
    const float* __restrict__ Jreg, const float* __restrict__ vt,
    const float* __restrict__ sd, const float* __restrict__ pdirs,
    const float* __restrict__ lbsw,
    float* __restrict__ JS, float* __restrict__ bj,
    unsigned short* __restrict__ pdT, unsigned short* __restrict__ wbf)
{
  __shared__ __align__(16) unsigned char su[38016];   // union: cvt tile / js red
  const int bid = blockIdx.x;
  const int t = threadIdx.x;

  if (bid < PREP_JS) {
    float* red = (float*)su;                 // [33][128]
    const int j = bid;
    if (t < 128) {
      float acc[33];
      #pragma unroll
      for (int e = 0; e < 33; ++e) acc[e] = 0.f;
      for (int v = t; v < V_; v += 128) {
        float r = Jreg[j*V_ + v];
        #pragma unroll
        for (int c = 0; c < 3; ++c) {
          acc[c*11 + 10] += r * vt[v*3 + c];
          #pragma unroll
          for (int l = 0; l < NB_; ++l)
            acc[c*11 + l] += r * sd[v*30 + c*10 + l];
        }
      }
      #pragma unroll
      for (int e = 0; e < 33; ++e) red[e*128 + t] = acc[e];
    }
    __syncthreads();
    if (t < 33) {
      float s = 0.f;
      for (int i = 0; i < 128; ++i) s += red[t*128 + i];
      int c = t / 11, l = t % 11;
      if (l == 10) bj[j*3 + c] = s;
      else         JS[(j*3 + c)*NB_ + l] = s;
    }
  } else if (bid < PREP_CVT) {
    float* tile = (float*)su;                // [288][33]
    const int bb = bid - PREP_JS;
    const int nt = bb / 3;
    const int c0 = (bb % 3) * 32;
    for (int i = t; i < P_*32; i += 256) {
      int k = i >> 5, c = i & 31;
      int gc = nt*96 + c0 + c;
      tile[k*33 + c] = (gc < N3) ? pdirs[(size_t)k*N3 + gc] : 0.f;
    }
    __syncthreads();
    for (int o = t; o < 32*P_; o += 256) {
      int c = o / P_, k = o % P_;
      pdT[((size_t)(nt*96 + c0 + c))*P_ + k] = f2bf(tile[k*33 + c]);
    }
  } else {
    const int bb = bid - PREP_CVT;
    const int total = 4096*96;
    for (int i = bb*256 + t; i < total; i += 64*256) {
      int v = i / 96, k = i - 96*v;
      float val = 0.f;
      if (v < V_) {
        if (k < 33) val = lbsw[(size_t)v*33 + k];
        else if (k < 66) {
          float w = lbsw[(size_t)v*33 + (k-33)];
          val = w - bf2f(f2bf(w));
        }
      }
      wbf[i] = f2bf(val);
    }
  }
}

// ---------------- kernel 2: joints, Rodrigues, FK, pose_feat (bf16) + Abf direct
__global__ __launch_bounds__(64) void k_pose(
    const float* __restrict__ betas, const float* __restrict__ go,
    const float* __restrict__ bp, const float* __restrict__ JS,
    const float* __restrict__ bj,
    unsigned short* __restrict__ pfb,   // [B][288] bf16
    unsigned short* __restrict__ Abf)   // [B][16][96] bf16 (hi/lo split)
{
  const int b = blockIdx.x;
  const int t = threadIdx.x;
  __shared__ float rot[J_][9];
  __shared__ float jnt[J_][3];
  __shared__ float Ash[J_][12];
  __shared__ float bsh[NB_];
  if (t < NB_) bsh[t] = betas[b*NB_ + t];
  __syncthreads();
  if (t < J_) {
    #pragma unroll
    for (int c = 0; c < 3; ++c) {
      float s = bj[t*3 + c];
      #pragma unroll
      for (int l = 0; l < NB_; ++l) s += bsh[l] * JS[(t*3 + c)*NB_ + l];
      jnt[t][c] = s;
    }
    float px, py, pz;
    if (t == 0) { px = go[b*3+0]; py = go[b*3+1]; pz = go[b*3+2]; }
    else {
      const float* p = bp + (size_t)b*((J_-1)*3) + (t-1)*3;
      px = p[0]; py = p[1]; pz = p[2];
    }
    float ax = px + 1e-8f, ay = py + 1e-8f, az = pz + 1e-8f;
    float ang = sqrtf(ax*ax + ay*ay + az*az);
    float inv = 1.0f / ang;
    float ux = px*inv, uy = py*inv, uz = pz*inv;
    float sn = sinf(ang), cs = cosf(ang);
    float K[9] = {0.f,-uz,uy,  uz,0.f,-ux,  -uy,ux,0.f};
    float R[9];
    #pragma unroll
    for (int r = 0; r < 3; ++r)
      #pragma unroll
      for (int c = 0; c < 3; ++c) {
        float k2 = K[r*3+0]*K[0*3+c] + K[r*3+1]*K[1*3+c] + K[r*3+2]*K[2*3+c];
        float id = (r == c) ? 1.f : 0.f;
        R[r*3+c] = id + sn*K[r*3+c] + (1.f - cs)*k2;
      }
    #pragma unroll
    for (int e = 0; e < 9; ++e) rot[t][e] = R[e];
    if (t >= 1) {
      #pragma unroll
      for (int e = 0; e < 9; ++e)
        pfb[(size_t)b*P_ + (t-1)*9 + e] = f2bf(R[e] - ((e==0||e==4||e==8) ? 1.f : 0.f));
    }
  }
  __syncthreads();
  if (t == 0) {
    float G[12];
    #pragma unroll
    for (int r = 0; r < 3; ++r) {
      G[r*4+0] = rot[0][r*3+0]; G[r*4+1] = rot[0][r*3+1];
      G[r*4+2] = rot[0][r*3+2]; G[r*4+3] = jnt[0][r];
    }
    for (int j = 0; j < J_; ++j) {
      if (j > 0) {
        float rel0 = jnt[j][0] - jnt[j-1][0];
        float rel1 = jnt[j][1] - jnt[j-1][1];
        float rel2 = jnt[j][2] - jnt[j-1][2];
        float N[12];
        #pragma unroll
        for (int r = 0; r < 3; ++r) {
          #pragma unroll
          for (int c = 0; c < 3; ++c)
            N[r*4+c] = G[r*4+0]*rot[j][0*3+c] + G[r*4+1]*rot[j][1*3+c] + G[r*4+2]*rot[j][2*3+c];
          N[r*4+3] = G[r*4+0]*rel0 + G[r*4+1]*rel1 + G[r*4+2]*rel2 + G[r*4+3];
        }
        #pragma unroll
        for (int e = 0; e < 12; ++e) G[e] = N[e];
      }
      #pragma unroll
      for (int r = 0; r < 3; ++r) {
        Ash[j][r*4+0] = G[r*4+0];
        Ash[j][r*4+1] = G[r*4+1];
        Ash[j][r*4+2] = G[r*4+2];
        Ash[j][r*4+3] = G[r*4+3] - (G[r*4+0]*jnt[j][0] + G[r*4+1]*jnt[j][1] + G[r*4+2]*jnt[j][2]);
      }
    }
  }
  __syncthreads();
  const float* Af = &Ash[0][0];
  for (int i = t; i < 1536; i += 64) {
    int n = i / 96, k = i - 96*n;
    int j = (k < 33) ? k : ((k < 66) ? (k - 33) : -1);
    float val = 0.f;
    if (j >= 0) {
      if (n < 12) val = Af[j*12 + n];
      else if (n < 15) {
        float tr = Af[j*12 + (n-12)*4 + 3];
        val = tr - bf2f(f2bf(tr));
      }
    }
    Abf[(size_t)b*1536 + i] = f2bf(val);
  }
}

// ---------------- FUSED kernel: MFMA GEMM (v_posed) + MFMA skinning, pipelined
// LDS 37.9 KB (4 blocks/CU by LDS); launch_bounds (256,2) keeps VGPR cap high
#define TS 17    // T row stride (floats): gcd(17,32)=1 -> conflict-free scalar reads

__global__ __launch_bounds__(256, 2) void k_gs(
    const float* __restrict__ betas,
    const float* __restrict__ vt, const float* __restrict__ sd,
    const unsigned short* __restrict__ pdT,
    const unsigned short* __restrict__ pfb_g,
    const float* __restrict__ transl,
    const unsigned short* __restrict__ wbf,   // [4096][96]
    const unsigned short* __restrict__ Abf,   // [B][16][96]
    float* __restrict__ out)
{
  __shared__ float s_beta[640];
  __shared__ float s_tr[192];           // transl for this block's 64 batches
  __shared__ float s_vp[64*100];        // v_posed tile [64 b][96 gc], stride 100
  __shared__ float s_T[4][32*TS];       // per-wave T tile (1 batch x 32 v), reused per h

  const int tid = threadIdx.x;
  const int nt = blockIdx.x, bt = blockIdx.y;
  const int b0 = bt*64;
  const int lane = tid & 63, wid = tid >> 6;
  const int wm = wid >> 1, wn = wid & 1;
  const int l15 = lane & 15, lg = lane >> 4;

  for (int i = tid; i < 64*NB_; i += 256) s_beta[i] = betas[(size_t)b0*NB_ + i];
  for (int i = tid; i < 192; i += 256) s_tr[i] = transl[(size_t)b0*3 + i];

  // hoisted skin a-frags (independent of GEMM; latency hides under phase 1)
  bf16x8 afr[2][3];
  #pragma unroll
  for (int mt = 0; mt < 2; ++mt) {
    const int vrow = nt*32 + mt*16 + l15;   // <= 3903 < 4096 (wbf zero-padded)
    #pragma unroll
    for (int ks = 0; ks < 3; ++ks)
      afr[mt][ks] = *(const bf16x8*)&wbf[(size_t)vrow*96 + ks*32 + lg*8];
  }
  __syncthreads();

  // ---- phase 1: GEMM (identical math to round-16) ----
  f32x4 acc[2][3];
  #pragma unroll
  for (int f = 0; f < 3; ++f) {
    int colL = wn*48 + f*16 + l15;
    int gc = nt*96 + colL;
    if (gc < N3) {
      int v = gc/3, c = gc - 3*v;
      float base = vt[gc];
      float sval[2][4];
      #pragma unroll
      for (int mi = 0; mi < 2; ++mi)
        #pragma unroll
        for (int reg = 0; reg < 4; ++reg) sval[mi][reg] = base;
      #pragma unroll
      for (int l = 0; l < NB_; ++l) {
        float sdv = sd[(size_t)v*30 + c*10 + l];
        #pragma unroll
        for (int mi = 0; mi < 2; ++mi) {
          int row_b = mi*32 + wm*16 + lg*4;
          #pragma unroll
          for (int reg = 0; reg < 4; ++reg)
            sval[mi][reg] += s_beta[(row_b+reg)*NB_ + l] * sdv;
        }
      }
      #pragma unroll
      for (int mi = 0; mi < 2; ++mi) {
        acc[mi][f][0]=sval[mi][0]; acc[mi][f][1]=sval[mi][1];
        acc[mi][f][2]=sval[mi][2]; acc[mi][f][3]=sval[mi][3];
      }
    } else {
      #pragma unroll
      for (int mi = 0; mi < 2; ++mi)
        acc[mi][f] = (f32x4){0.f,0.f,0.f,0.f};
    }
  }

  const unsigned short* __restrict__ pfrow0 =
      pfb_g + (size_t)(b0 + wm*16 + l15)*P_ + lg*8;
  const unsigned short* __restrict__ pfrow1 =
      pfb_g + (size_t)(b0 + 32 + wm*16 + l15)*P_ + lg*8;
  const unsigned short* __restrict__ pdrow =
      pdT + (size_t)(nt*96 + wn*48 + l15)*P_ + lg*8;
  #pragma unroll
  for (int ks = 0; ks < 9; ++ks) {
    bf16x8 a0 = *(const bf16x8*)(pfrow0 + ks*32);
    bf16x8 a1 = *(const bf16x8*)(pfrow1 + ks*32);
    #pragma unroll
    for (int f = 0; f < 3; ++f) {
      bf16x8 b = *(const bf16x8*)(pdrow + (size_t)f*16*P_ + ks*32);
      acc[0][f] = __builtin_amdgcn_mfma_f32_16x16x32_bf16(a0, b, acc[0][f], 0, 0, 0);
      acc[1][f] = __builtin_amdgcn_mfma_f32_16x16x32_bf16(a1, b, acc[1][f], 0, 0, 0);
    }
  }

  // prefetch g=0 skin b-frags (hides under phase-2 LDS writes + barrier)
  bf16x8 bcur[2][3];
  #pragma unroll
  for (int h = 0; h < 2; ++h) {
    const unsigned short* Ab = Abf + (size_t)(b0 + wid*16 + h)*1536;
    #pragma unroll
    for (int ks = 0; ks < 3; ++ks)
      bcur[h][ks] = *(const bf16x8*)&Ab[l15*96 + ks*32 + lg*8];
  }

  // ---- phase 2: v_posed -> LDS ----
  #pragma unroll
  for (int f = 0; f < 3; ++f) {
    int colL = wn*48 + f*16 + l15;
    #pragma unroll
    for (int mi = 0; mi < 2; ++mi) {
      int row_b = mi*32 + wm*16 + lg*4;
      #pragma unroll
      for (int reg = 0; reg < 4; ++reg)
        s_vp[(row_b+reg)*100 + colL] = acc[mi][f][reg];
    }
  }
  __syncthreads();

  // ---- phase 3: pipelined MFMA skinning (shared T tile, sequential h) ----
  float* Tw = &s_T[wid][0];
  const int vl = lane & 31;
  const int v = nt*32 + vl;

  float pxc[2], pyc[2], pzc[2];
  #pragma unroll
  for (int h = 0; h < 2; ++h) {
    int bl = wid*16 + h;
    pxc[h] = s_vp[bl*100 + vl*3 + 0];
    pyc[h] = s_vp[bl*100 + vl*3 + 1];
    pzc[h] = s_vp[bl*100 + vl*3 + 2];
  }

  #pragma unroll 2
  for (int g = 0; g < 8; ++g) {
    bf16x8 bnxt[2][3];
    float pxn[2] = {0.f,0.f}, pyn[2] = {0.f,0.f}, pzn[2] = {0.f,0.f};
    if (g < 7) {
      #pragma unroll
      for (int h = 0; h < 2; ++h) {
        const unsigned short* Ab = Abf + (size_t)(b0 + wid*16 + (g+1)*2 + h)*1536;
        #pragma unroll
        for (int ks = 0; ks < 3; ++ks)
          bnxt[h][ks] = *(const bf16x8*)&Ab[l15*96 + ks*32 + lg*8];
        int bln = wid*16 + (g+1)*2 + h;
        pxn[h] = s_vp[bln*100 + vl*3 + 0];
        pyn[h] = s_vp[bln*100 + vl*3 + 1];
        pzn[h] = s_vp[bln*100 + vl*3 + 2];
      }
    }

    #pragma unroll
    for (int h = 0; h < 2; ++h) {
      f32x4 t0 = {0.f,0.f,0.f,0.f}, t1 = t0;
      #pragma unroll
      for (int ks = 0; ks < 3; ++ks) {
        t0 = __builtin_amdgcn_mfma_f32_16x16x32_bf16(afr[0][ks], bcur[h][ks], t0, 0, 0, 0);
        t1 = __builtin_amdgcn_mfma_f32_16x16x32_bf16(afr[1][ks], bcur[h][ks], t1, 0, 0, 0);
      }
      // C layout: col=lane&15 (n), row=(lane>>4)*4+reg (vertex-local)
      #pragma unroll
      for (int reg = 0; reg < 4; ++reg) {
        Tw[(lg*4+reg)*TS + l15]    = t0[reg];
        Tw[(16+lg*4+reg)*TS + l15] = t1[reg];
      }
      // consume batch g*2+h (in-wave DS ordering: writes above retire first)
      {
        const int bl2 = wid*16 + g*2 + h;
        const int b2  = b0 + bl2;
        const float* Tr = Tw + vl*TS;
        float o0 = Tr[0]*pxc[h] + Tr[1]*pyc[h] + Tr[2]*pzc[h]  + Tr[3]  + Tr[12] + s_tr[bl2*3+0];
        float o1 = Tr[4]*pxc[h] + Tr[5]*pyc[h] + Tr[6]*pzc[h]  + Tr[7]  + Tr[13] + s_tr[bl2*3+1];
        float o2 = Tr[8]*pxc[h] + Tr[9]*pyc[h] + Tr[10]*pzc[h] + Tr[11] + Tr[14] + s_tr[bl2*3+2];
        if (lane < 32 && v < V_) {
          size_t po = (size_t)b2*N3 + (size_t)v*3;
          out[po+0] = o0; out[po+1] = o1; out[po+2] = o2;
        }
      }
    }

    if (g < 7) {
      #pragma unroll
      for (int h = 0; h < 2; ++h) {
        #pragma unroll
        for (int ks = 0; ks < 3; ++ks)
          bcur[h][ks] = bnxt[h][ks];
        pxc[h] = pxn[h]; pyc[h] = pyn[h]; pzc[h] = pzn[h];
      }
    }
  }
}

extern "C" void kernel_launch(void* const* d_in, const int* in_sizes, int n_in,
                              void* d_out, int out_size, void* d_ws, size_t ws_size,
                              hipStream_t stream) {
  const float* betas  = (const float*)d_in[0];
  const float* go     = (const float*)d_in[1];
  const float* bp     = (const float*)d_in[2];
  const float* transl = (const float*)d_in[3];
  const float* vt     = (const float*)d_in[4];
  const float* sd     = (const float*)d_in[5];
  const float* pdirs  = (const float*)d_in[6];
  const float* Jreg   = (const float*)d_in[7];
  const float* lbsw   = (const float*)d_in[8];
  float* out = (float*)d_out;
  char* wb = (char*)d_ws;

  // round-14/15-proven fused workspace layout (ws_size >= 12,899,328 verified).
  float* JS            = (float*)(wb + 0);
  float* bj            = (float*)(wb + 4096);
  unsigned short* pfb  = (unsigned short*)(wb + 1630720);   // 589,824
  unsigned short* Abf  = (unsigned short*)(wb + 2221056);   // 3,145,728
  unsigned short* pdT  = (unsigned short*)(wb + 5366784);   // 6,746,112
  unsigned short* wbf  = (unsigned short*)(wb + 12112896);  // 786,432 -> ends 12,899,328

  hipLaunchKernelGGL(k_prep, dim3(PREP_NB), dim3(256), 0, stream,
                     Jreg, vt, sd, pdirs, lbsw, JS, bj, pdT, wbf);
  hipLaunchKernelGGL(k_pose, dim3(B_), dim3(64), 0, stream,
                     betas, go, bp, JS, bj, pfb, Abf);
  hipLaunchKernelGGL(k_gs,   dim3(NT_, B_/64), dim3(256), 0, stream,
                     betas, vt, sd, pdT, pfb, transl, wbf, Abf, out);
}

// Round 19
// 104.821 us; speedup vs baseline: 1.3191x; 1.0243x over previous
//
#include <hip/hip_runtime.h>
#include <math.h>

#define B_  1024
#define V_  3889
#define J_  33
#define NB_ 10
#define P_  288
#define N3  11667
#define NT_ 122            // 122 tiles of 96 cols (32 verts)
#define NPAD (NT_*96)      // 11712

typedef short bf16x8 __attribute__((ext_vector_type(8)));
typedef float f32x4  __attribute__((ext_vector_type(4)));

__device__ __forceinline__ unsigned short f2bf(float f) {
  union { float f; unsigned u; } v; v.f = f;
  unsigned r = v.u + 0x7FFFu + ((v.u >> 16) & 1u);
  return (unsigned short)(r >> 16);
}
__device__ __forceinline__ float bf2f(unsigned short h) {
  union { unsigned u; float f; } v; v.u = ((unsigned)h) << 16; return v.f;
}

// ---------------- kernel 1: fused prep (js | cvt | wbf roles by blockIdx)
#define PREP_JS   33
#define PREP_CVT  399
#define PREP_NB   463

__global__ __launch_bounds__(256) void k_prep(
    const float* __restrict__ Jreg, const float* __restrict__ vt,
    const float* __restrict__ sd, const float* __restrict__ pdirs,
    const float* __restrict__ lbsw,
    float* __restrict__ JS, float* __restrict__ bj,
    unsigned short* __restrict__ pdT, unsigned short* __restrict__ wbf)
{
  __shared__ __align__(16) unsigned char su[38016];   // union: cvt tile / js red
  const int bid = blockIdx.x;
  const int t = threadIdx.x;

  if (bid < PREP_JS) {
    float* red = (float*)su;                 // [33][128]
    const int j = bid;
    if (t < 128) {
      float acc[33];
      #pragma unroll
      for (int e = 0; e < 33; ++e) acc[e] = 0.f;
      for (int v = t; v < V_; v += 128) {
        float r = Jreg[j*V_ + v];
        #pragma unroll
        for (int c = 0; c < 3; ++c) {
          acc[c*11 + 10] += r * vt[v*3 + c];
          #pragma unroll
          for (int l = 0; l < NB_; ++l)
            acc[c*11 + l] += r * sd[v*30 + c*10 + l];
        }
      }
      #pragma unroll
      for (int e = 0; e < 33; ++e) red[e*128 + t] = acc[e];
    }
    __syncthreads();
    if (t < 33) {
      float s = 0.f;
      for (int i = 0; i < 128; ++i) s += red[t*128 + i];
      int c = t / 11, l = t % 11;
      if (l == 10) bj[j*3 + c] = s;
      else         JS[(j*3 + c)*NB_ + l] = s;
    }
  } else if (bid < PREP_CVT) {
    float* tile = (float*)su;                // [288][33]
    const int bb = bid - PREP_JS;
    const int nt = bb / 3;
    const int c0 = (bb % 3) * 32;
    for (int i = t; i < P_*32; i += 256) {
      int k = i >> 5, c = i & 31;
      int gc = nt*96 + c0 + c;
      tile[k*33 + c] = (gc < N3) ? pdirs[(size_t)k*N3 + gc] : 0.f;
    }
    __syncthreads();
    for (int o = t; o < 32*P_; o += 256) {
      int c = o / P_, k = o % P_;
      pdT[((size_t)(nt*96 + c0 + c))*P_ + k] = f2bf(tile[k*33 + c]);
    }
  } else {
    const int bb = bid - PREP_CVT;
    const int total = 4096*96;
    for (int i = bb*256 + t; i < total; i += 64*256) {
      int v = i / 96, k = i - 96*v;
      float val = 0.f;
      if (v < V_) {
        if (k < 33) val = lbsw[(size_t)v*33 + k];
        else if (k < 66) {
          float w = lbsw[(size_t)v*33 + (k-33)];
          val = w - bf2f(f2bf(w));
        }
      }
      wbf[i] = f2bf(val);
    }
  }
}

// ---------------- kernel 2: joints, Rodrigues, FK, pose_feat (bf16) + Abf direct
__global__ __launch_bounds__(64) void k_pose(
    const float* __restrict__ betas, const float* __restrict__ go,
    const float* __restrict__ bp, const float* __restrict__ JS,
    const float* __restrict__ bj,
    unsigned short* __restrict__ pfb,   // [B][288] bf16
    unsigned short* __restrict__ Abf)   // [B][16][96] bf16 (hi/lo split)
{
  const int b = blockIdx.x;
  const int t = threadIdx.x;
  __shared__ float rot[J_][9];
  __shared__ float jnt[J_][3];
  __shared__ float Ash[J_][12];
  __shared__ float bsh[NB_];
  if (t < NB_) bsh[t] = betas[b*NB_ + t];
  __syncthreads();
  if (t < J_) {
    #pragma unroll
    for (int c = 0; c < 3; ++c) {
      float s = bj[t*3 + c];
      #pragma unroll
      for (int l = 0; l < NB_; ++l) s += bsh[l] * JS[(t*3 + c)*NB_ + l];
      jnt[t][c] = s;
    }
    float px, py, pz;
    if (t == 0) { px = go[b*3+0]; py = go[b*3+1]; pz = go[b*3+2]; }
    else {
      const float* p = bp + (size_t)b*((J_-1)*3) + (t-1)*3;
      px = p[0]; py = p[1]; pz = p[2];
    }
    float ax = px + 1e-8f, ay = py + 1e-8f, az = pz + 1e-8f;
    float ang = sqrtf(ax*ax + ay*ay + az*az);
    float inv = 1.0f / ang;
    float ux = px*inv, uy = py*inv, uz = pz*inv;
    float sn = sinf(ang), cs = cosf(ang);
    float K[9] = {0.f,-uz,uy,  uz,0.f,-ux,  -uy,ux,0.f};
    float R[9];
    #pragma unroll
    for (int r = 0; r < 3; ++r)
      #pragma unroll
      for (int c = 0; c < 3; ++c) {
        float k2 = K[r*3+0]*K[0*3+c] + K[r*3+1]*K[1*3+c] + K[r*3+2]*K[2*3+c];
        float id = (r == c) ? 1.f : 0.f;
        R[r*3+c] = id + sn*K[r*3+c] + (1.f - cs)*k2;
      }
    #pragma unroll
    for (int e = 0; e < 9; ++e) rot[t][e] = R[e];
    if (t >= 1) {
      #pragma unroll
      for (int e = 0; e < 9; ++e)
        pfb[(size_t)b*P_ + (t-1)*9 + e] = f2bf(R[e] - ((e==0||e==4||e==8) ? 1.f : 0.f));
    }
  }
  __syncthreads();
  if (t == 0) {
    float G[12];
    #pragma unroll
    for (int r = 0; r < 3; ++r) {
      G[r*4+0] = rot[0][r*3+0]; G[r*4+1] = rot[0][r*3+1];
      G[r*4+2] = rot[0][r*3+2]; G[r*4+3] = jnt[0][r];
    }
    for (int j = 0; j < J_; ++j) {
      if (j > 0) {
        float rel0 = jnt[j][0] - jnt[j-1][0];
        float rel1 = jnt[j][1] - jnt[j-1][1];
        float rel2 = jnt[j][2] - jnt[j-1][2];
        float N[12];
        #pragma unroll
        for (int r = 0; r < 3; ++r) {
          #pragma unroll
          for (int c = 0; c < 3; ++c)
            N[r*4+c] = G[r*4+0]*rot[j][0*3+c] + G[r*4+1]*rot[j][1*3+c] + G[r*4+2]*rot[j][2*3+c];
          N[r*4+3] = G[r*4+0]*rel0 + G[r*4+1]*rel1 + G[r*4+2]*rel2 + G[r*4+3];
        }
        #pragma unroll
        for (int e = 0; e < 12; ++e) G[e] = N[e];
      }
      #pragma unroll
      for (int r = 0; r < 3; ++r) {
        Ash[j][r*4+0] = G[r*4+0];
        Ash[j][r*4+1] = G[r*4+1];
        Ash[j][r*4+2] = G[r*4+2];
        Ash[j][r*4+3] = G[r*4+3] - (G[r*4+0]*jnt[j][0] + G[r*4+1]*jnt[j][1] + G[r*4+2]*jnt[j][2]);
      }
    }
  }
  __syncthreads();
  const float* Af = &Ash[0][0];
  for (int i = t; i < 1536; i += 64) {
    int n = i / 96, k = i - 96*n;
    int j = (k < 33) ? k : ((k < 66) ? (k - 33) : -1);
    float val = 0.f;
    if (j >= 0) {
      if (n < 12) val = Af[j*12 + n];
      else if (n < 15) {
        float tr = Af[j*12 + (n-12)*4 + 3];
        val = tr - bf2f(f2bf(tr));
      }
    }
    Abf[(size_t)b*1536 + i] = f2bf(val);
  }
}

// ---------------- FUSED kernel: round-16 body + bijective XCD swizzle (T1)
#define TS 17    // T row stride (floats): gcd(17,32)=1 -> conflict-free scalar reads

__global__ __launch_bounds__(256, 2) void k_gs(
    const float* __restrict__ betas,
    const float* __restrict__ vt, const float* __restrict__ sd,
    const unsigned short* __restrict__ pdT,
    const unsigned short* __restrict__ pfb_g,
    const float* __restrict__ transl,
    const unsigned short* __restrict__ wbf,   // [4096][96]
    const unsigned short* __restrict__ Abf,   // [B][16][96]
    float* __restrict__ out)
{
  __shared__ float s_beta[640];
  __shared__ float s_tr[192];           // transl for this block's 64 batches
  __shared__ float s_vp[64*100];        // v_posed tile [64 b][96 gc], stride 100
  __shared__ float s_T[4][2*32*TS];     // per-wave private T tiles

  // XCD-aware bijective remap: 1952 blocks, 8 XCDs, 244 blocks each.
  // Each XCD gets a contiguous wg range = ~15 contiguous nt values x all bt
  // -> its pdT slice (~840 KB) + Abf (3.1 MB) stay L2-resident.
  const int hw  = blockIdx.x;
  const int wg  = (hw & 7) * 244 + (hw >> 3);   // 1952 % 8 == 0 -> bijective
  const int nt  = wg >> 4;                       // 0..121
  const int bt  = wg & 15;                       // 0..15
  const int b0  = bt*64;

  const int tid = threadIdx.x;
  const int lane = tid & 63, wid = tid >> 6;
  const int wm = wid >> 1, wn = wid & 1;
  const int l15 = lane & 15, lg = lane >> 4;

  for (int i = tid; i < 64*NB_; i += 256) s_beta[i] = betas[(size_t)b0*NB_ + i];
  for (int i = tid; i < 192; i += 256) s_tr[i] = transl[(size_t)b0*3 + i];

  // hoisted skin a-frags (latency hides under phase 1)
  bf16x8 afr[2][3];
  #pragma unroll
  for (int mt = 0; mt < 2; ++mt) {
    const int vrow = nt*32 + mt*16 + l15;   // <= 3903 < 4096 (wbf zero-padded)
    #pragma unroll
    for (int ks = 0; ks < 3; ++ks)
      afr[mt][ks] = *(const bf16x8*)&wbf[(size_t)vrow*96 + ks*32 + lg*8];
  }
  __syncthreads();

  // ---- phase 1: GEMM ----
  f32x4 acc[2][3];
  #pragma unroll
  for (int f = 0; f < 3; ++f) {
    int colL = wn*48 + f*16 + l15;
    int gc = nt*96 + colL;
    if (gc < N3) {
      int v = gc/3, c = gc - 3*v;
      float base = vt[gc];
      float sval[2][4];
      #pragma unroll
      for (int mi = 0; mi < 2; ++mi)
        #pragma unroll
        for (int reg = 0; reg < 4; ++reg) sval[mi][reg] = base;
      #pragma unroll
      for (int l = 0; l < NB_; ++l) {
        float sdv = sd[(size_t)v*30 + c*10 + l];
        #pragma unroll
        for (int mi = 0; mi < 2; ++mi) {
          int row_b = mi*32 + wm*16 + lg*4;
          #pragma unroll
          for (int reg = 0; reg < 4; ++reg)
            sval[mi][reg] += s_beta[(row_b+reg)*NB_ + l] * sdv;
        }
      }
      #pragma unroll
      for (int mi = 0; mi < 2; ++mi) {
        acc[mi][f][0]=sval[mi][0]; acc[mi][f][1]=sval[mi][1];
        acc[mi][f][2]=sval[mi][2]; acc[mi][f][3]=sval[mi][3];
      }
    } else {
      #pragma unroll
      for (int mi = 0; mi < 2; ++mi)
        acc[mi][f] = (f32x4){0.f,0.f,0.f,0.f};
    }
  }

  const unsigned short* __restrict__ pfrow0 =
      pfb_g + (size_t)(b0 + wm*16 + l15)*P_ + lg*8;
  const unsigned short* __restrict__ pfrow1 =
      pfb_g + (size_t)(b0 + 32 + wm*16 + l15)*P_ + lg*8;
  const unsigned short* __restrict__ pdrow =
      pdT + (size_t)(nt*96 + wn*48 + l15)*P_ + lg*8;
  #pragma unroll
  for (int ks = 0; ks < 9; ++ks) {
    bf16x8 a0 = *(const bf16x8*)(pfrow0 + ks*32);
    bf16x8 a1 = *(const bf16x8*)(pfrow1 + ks*32);
    #pragma unroll
    for (int f = 0; f < 3; ++f) {
      bf16x8 b = *(const bf16x8*)(pdrow + (size_t)f*16*P_ + ks*32);
      acc[0][f] = __builtin_amdgcn_mfma_f32_16x16x32_bf16(a0, b, acc[0][f], 0, 0, 0);
      acc[1][f] = __builtin_amdgcn_mfma_f32_16x16x32_bf16(a1, b, acc[1][f], 0, 0, 0);
    }
  }

  // prefetch g=0 skin b-frags
  bf16x8 bcur[2][3];
  #pragma unroll
  for (int h = 0; h < 2; ++h) {
    const unsigned short* Ab = Abf + (size_t)(b0 + wid*16 + h)*1536;
    #pragma unroll
    for (int ks = 0; ks < 3; ++ks)
      bcur[h][ks] = *(const bf16x8*)&Ab[l15*96 + ks*32 + lg*8];
  }

  // ---- phase 2: v_posed -> LDS ----
  #pragma unroll
  for (int f = 0; f < 3; ++f) {
    int colL = wn*48 + f*16 + l15;
    #pragma unroll
    for (int mi = 0; mi < 2; ++mi) {
      int row_b = mi*32 + wm*16 + lg*4;
      #pragma unroll
      for (int reg = 0; reg < 4; ++reg)
        s_vp[(row_b+reg)*100 + colL] = acc[mi][f][reg];
    }
  }
  __syncthreads();

  // ---- phase 3: pipelined MFMA skinning ----
  float* Tw = &s_T[wid][0];
  const int h2 = lane >> 5, vl = lane & 31;
  const int v = nt*32 + vl;

  float pxc = s_vp[(wid*16 + h2)*100 + vl*3 + 0];
  float pyc = s_vp[(wid*16 + h2)*100 + vl*3 + 1];
  float pzc = s_vp[(wid*16 + h2)*100 + vl*3 + 2];

  #pragma unroll 2
  for (int g = 0; g < 8; ++g) {
    bf16x8 bnxt[2][3];
    float pxn = 0.f, pyn = 0.f, pzn = 0.f;
    if (g < 7) {
      #pragma unroll
      for (int h = 0; h < 2; ++h) {
        const unsigned short* Ab = Abf + (size_t)(b0 + wid*16 + (g+1)*2 + h)*1536;
        #pragma unroll
        for (int ks = 0; ks < 3; ++ks)
          bnxt[h][ks] = *(const bf16x8*)&Ab[l15*96 + ks*32 + lg*8];
      }
      int bln = wid*16 + (g+1)*2 + h2;
      pxn = s_vp[bln*100 + vl*3 + 0];
      pyn = s_vp[bln*100 + vl*3 + 1];
      pzn = s_vp[bln*100 + vl*3 + 2];
    }

    #pragma unroll
    for (int h = 0; h < 2; ++h) {
      f32x4 t0 = {0.f,0.f,0.f,0.f}, t1 = t0;
      #pragma unroll
      for (int ks = 0; ks < 3; ++ks) {
        t0 = __builtin_amdgcn_mfma_f32_16x16x32_bf16(afr[0][ks], bcur[h][ks], t0, 0, 0, 0);
        t1 = __builtin_amdgcn_mfma_f32_16x16x32_bf16(afr[1][ks], bcur[h][ks], t1, 0, 0, 0);
      }
      #pragma unroll
      for (int reg = 0; reg < 4; ++reg) {
        Tw[h*32*TS + (lg*4+reg)*TS + l15]      = t0[reg];
        Tw[h*32*TS + (16+lg*4+reg)*TS + l15]   = t1[reg];
      }
    }
    {
      const int bl2 = wid*16 + g*2 + h2;
      const int b2  = b0 + bl2;
      const float* Tr = Tw + h2*32*TS + vl*TS;
      float o0 = Tr[0]*pxc + Tr[1]*pyc + Tr[2]*pzc  + Tr[3]  + Tr[12] + s_tr[bl2*3+0];
      float o1 = Tr[4]*pxc + Tr[5]*pyc + Tr[6]*pzc  + Tr[7]  + Tr[13] + s_tr[bl2*3+1];
      float o2 = Tr[8]*pxc + Tr[9]*pyc + Tr[10]*pzc + Tr[11] + Tr[14] + s_tr[bl2*3+2];
      if (v < V_) {
        size_t po = (size_t)b2*N3 + (size_t)v*3;
        out[po+0] = o0; out[po+1] = o1; out[po+2] = o2;
      }
    }
    if (g < 7) {
      #pragma unroll
      for (int h = 0; h < 2; ++h)
        #pragma unroll
        for (int ks = 0; ks < 3; ++ks)
          bcur[h][ks] = bnxt[h][ks];
      pxc = pxn; pyc = pyn; pzc = pzn;
    }
  }
}

extern "C" void kernel_launch(void* const* d_in, const int* in_sizes, int n_in,
                              void* d_out, int out_size, void* d_ws, size_t ws_size,
                              hipStream_t stream) {
  const float* betas  = (const float*)d_in[0];
  const float* go     = (const float*)d_in[1];
  const float* bp     = (const float*)d_in[2];
  const float* transl = (const float*)d_in[3];
  const float* vt     = (const float*)d_in[4];
  const float* sd     = (const float*)d_in[5];
  const float* pdirs  = (const float*)d_in[6];
  const float* Jreg   = (const float*)d_in[7];
  const float* lbsw   = (const float*)d_in[8];
  float* out = (float*)d_out;
  char* wb = (char*)d_ws;

  // round-14/15-proven fused workspace layout (ws_size >= 12,899,328 verified).
  float* JS            = (float*)(wb + 0);
  float* bj            = (float*)(wb + 4096);
  unsigned short* pfb  = (unsigned short*)(wb + 1630720);   // 589,824
  unsigned short* Abf  = (unsigned short*)(wb + 2221056);   // 3,145,728
  unsigned short* pdT  = (unsigned short*)(wb + 5366784);   // 6,746,112
  unsigned short* wbf  = (unsigned short*)(wb + 12112896);  // 786,432 -> ends 12,899,328

  hipLaunchKernelGGL(k_prep, dim3(PREP_NB), dim3(256), 0, stream,
                     Jreg, vt, sd, pdirs, lbsw, JS, bj, pdT, wbf);
  hipLaunchKernelGGL(k_pose, dim3(B_), dim3(64), 0, stream,
                     betas, go, bp, JS, bj, pfb, Abf);
  hipLaunchKernelGGL(k_gs,   dim3(NT_*16), dim3(256), 0, stream,
                     betas, vt, sd, pdT, pfb, transl, wbf, Abf, out);
}